// Round 1
// baseline (185.314 us; speedup 1.0000x reference)
//
#include <hip/hip_runtime.h>
#include <stdint.h>

typedef short bf16x8 __attribute__((ext_vector_type(8)));
typedef float f32x4 __attribute__((ext_vector_type(4)));

#define N_IMG 32
#define C_IN 256
#define H_IN 56
#define W_IN 56
#define K_OUT 256
#define H_OUT 54
#define W_OUT 54
#define HW_OUT 2916          // 54*54
#define M_PIX 93312          // 32*2916
#define CHW_OUT 746496       // 256*2916

#define XT_ELEMS ((size_t)N_IMG * H_IN * W_IN * C_IN)   // 25,690,112
#define WT_ELEMS ((size_t)9 * K_OUT * C_IN)             // 589,824

// -------- transform 1: x NCHW int32 -> NHWC bf16 (values 0..7, exact) --------
__global__ __launch_bounds__(256) void xform_x(const int* __restrict__ x,
                                               unsigned short* __restrict__ xt) {
    const int bid = blockIdx.x;          // n*56 + h
    const int n = bid / H_IN;
    const int h = bid % H_IN;
    const int c = threadIdx.x;
    const int* src = x + ((size_t)((n * C_IN + c) * H_IN + h)) * W_IN;
    unsigned short* dst = xt + ((size_t)(n * H_IN + h) * W_IN) * C_IN + c;
    #pragma unroll
    for (int w0 = 0; w0 < W_IN; w0 += 4) {
        int4 v = *(const int4*)(src + w0);
        int a[4] = {v.x, v.y, v.z, v.w};
        #pragma unroll
        for (int j = 0; j < 4; ++j) {
            int q = a[j] < 0 ? 0 : (a[j] > 7 ? 7 : a[j]);
            // small ints are exact in bf16: bf16 bits == fp32 bits >> 16
            dst[(size_t)(w0 + j) * C_IN] = (unsigned short)(__float_as_uint((float)q) >> 16);
        }
    }
}

// -------- transform 2: weight OIHW fp32 -> [rs][k][c] bf16 (trunc to int) --------
__global__ __launch_bounds__(256) void xform_w(const float* __restrict__ w,
                                               unsigned short* __restrict__ wt) {
    const int k = blockIdx.x;
    const int c = threadIdx.x;
    const float* src = w + ((size_t)k * C_IN + c) * 9;
    #pragma unroll
    for (int rs = 0; rs < 9; ++rs) {
        int iv = (int)src[rs];   // truncation == astype(int32); values 0..6 exact
        wt[((size_t)rs * K_OUT + k) * C_IN + c] = (unsigned short)(__float_as_uint((float)iv) >> 16);
    }
}

// -------- async global->LDS (width 16) --------
__device__ __forceinline__ void gload_lds16(const void* g, void* l) {
    __builtin_amdgcn_global_load_lds(
        (const __attribute__((address_space(1))) uint32_t*)g,
        (__attribute__((address_space(3))) uint32_t*)l,
        16, 0, 0);
}

// -------- main implicit-GEMM conv: BM=128 pixels, BN=128 ch, BK=64, 4 waves --------
__global__ __launch_bounds__(256) void conv_mfma(const unsigned short* __restrict__ xt,
                                                 const unsigned short* __restrict__ wt,
                                                 float* __restrict__ out) {
    __shared__ unsigned short As[128 * 64];   // [pixel_row][c] swizzled chunks, 16 KiB
    __shared__ unsigned short Bs[128 * 64];   // [out_ch_row][c] swizzled chunks, 16 KiB

    const int t   = threadIdx.x;
    const int l   = t & 63;
    const int wid = t >> 6;
    const int wr  = wid >> 1;    // wave row (0..1) -> 64 pixels
    const int wc  = wid & 1;     // wave col (0..1) -> 64 channels
    const int mb  = blockIdx.x >> 1;   // 729 M-blocks
    const int nb  = blockIdx.x & 1;    // 2 N-blocks

    // staging lane geometry: per load i, lane covers row = i*32 + wid*8 + (l>>3),
    // LDS chunk slot (l&7). Both-sides swizzle: slot s of row holds data chunk s^(row&7).
    // Here row&7 == (l>>3), so source chunk = (l&7) ^ (l>>3): per-lane constant.
    const int cs = (((l & 7) ^ (l >> 3)) << 4);  // byte offset within 128B pixel row

    int abase[4], bbase[4];
    #pragma unroll
    for (int i = 0; i < 4; ++i) {
        const int row = i * 32 + wid * 8 + (l >> 3);
        const int m   = mb * 128 + row;
        const int n   = m / HW_OUT;
        const int rem = m - n * HW_OUT;
        const int ho  = rem / W_OUT;
        const int wo  = rem - ho * W_OUT;
        abase[i] = (((n * H_IN + ho) * W_IN + wo) << 9) + cs;   // *512 B per NHWC pixel
        bbase[i] = ((nb * 128 + row) << 9) + cs;                // *512 B per k row of Wt[rs]
    }

    f32x4 acc[4][4];
    #pragma unroll
    for (int i = 0; i < 4; ++i)
        #pragma unroll
        for (int j = 0; j < 4; ++j)
            acc[i][j] = (f32x4){0.f, 0.f, 0.f, 0.f};

    const char* xb = (const char*)xt;
    const char* wb = (const char*)wt;
    char* Ab = (char*)As;
    char* Bb = (char*)Bs;

    const int lrow = l & 15;
    const int lk   = (l >> 4) << 4;   // fragment k-subchunk byte offset (0/16/32/48)

    for (int ks = 0; ks < 36; ++ks) {
        const int rs  = ks >> 2;                   // tap index 0..8
        const int c0b = (ks & 3) << 7;             // c-chunk byte offset (0..384B)
        const int r   = rs / 3;
        const int s   = rs - r * 3;
        const int astep = ((r * W_IN + s) << 9) + c0b;
        const int bstep = rs * (K_OUT * C_IN * 2) + c0b;

        __syncthreads();   // previous tile's reads complete before overwrite
        #pragma unroll
        for (int i = 0; i < 4; ++i) {
            gload_lds16(xb + abase[i] + astep, Ab + i * 4096 + wid * 1024);
            gload_lds16(wb + bbase[i] + bstep, Bb + i * 4096 + wid * 1024);
        }
        __syncthreads();   // compiler drains vmcnt(0) before barrier -> tiles ready

        bf16x8 af[4][2], bfv[4][2];
        #pragma unroll
        for (int f = 0; f < 4; ++f) {
            const int arow = wr * 64 + f * 16 + lrow;
            const int brow = wc * 64 + f * 16 + lrow;
            const int asw = (arow & 7) << 4;
            const int bsw = (brow & 7) << 4;
            #pragma unroll
            for (int kk = 0; kk < 2; ++kk) {
                const int chb = (kk << 6) + lk;
                af[f][kk]  = *(const bf16x8*)(Ab + (arow << 7) + (chb ^ asw));
                bfv[f][kk] = *(const bf16x8*)(Bb + (brow << 7) + (chb ^ bsw));
            }
        }
        #pragma unroll
        for (int mf = 0; mf < 4; ++mf)
            #pragma unroll
            for (int nf = 0; nf < 4; ++nf)
                #pragma unroll
                for (int kk = 0; kk < 2; ++kk)
                    acc[mf][nf] = __builtin_amdgcn_mfma_f32_16x16x32_bf16(
                        af[mf][kk], bfv[nf][kk], acc[mf][nf], 0, 0, 0);
    }

    // epilogue: C/D layout col=lane&15, row=(lane>>4)*4+reg (m89-verified)
    const int c16    = l & 15;
    const int p4     = (l >> 4) << 2;
    const int chbase = nb * 128 + wc * 64 + c16;
    #pragma unroll
    for (int mf = 0; mf < 4; ++mf) {
        #pragma unroll
        for (int j = 0; j < 4; ++j) {
            const int m   = mb * 128 + wr * 64 + mf * 16 + p4 + j;
            const int n   = m / HW_OUT;
            const int rem = m - n * HW_OUT;
            float* obase = out + (size_t)n * CHW_OUT + rem;
            #pragma unroll
            for (int nf = 0; nf < 4; ++nf)
                obase[(size_t)(chbase + nf * 16) * HW_OUT] = acc[mf][nf][j];
        }
    }
}

// -------- fallback (only if ws too small): naive direct conv, exact --------
__global__ __launch_bounds__(256) void conv_naive(const int* __restrict__ x,
                                                  const float* __restrict__ w,
                                                  float* __restrict__ out) {
    int idx = blockIdx.x * 256 + threadIdx.x;
    if (idx >= N_IMG * K_OUT * HW_OUT) return;
    const int wo = idx % W_OUT;
    int tmp = idx / W_OUT;
    const int ho = tmp % H_OUT; tmp /= H_OUT;
    const int k = tmp % K_OUT;
    const int n = tmp / K_OUT;
    float acc = 0.f;
    for (int c = 0; c < C_IN; ++c) {
        const int* xp = x + ((size_t)((n * C_IN + c) * H_IN + ho)) * W_IN + wo;
        const float* wp = w + ((size_t)(k * C_IN + c)) * 9;
        #pragma unroll
        for (int r = 0; r < 3; ++r)
            #pragma unroll
            for (int s = 0; s < 3; ++s) {
                int xv = xp[r * W_IN + s];
                xv = xv < 0 ? 0 : (xv > 7 ? 7 : xv);
                acc += (float)xv * (float)(int)wp[r * 3 + s];
            }
    }
    out[idx] = acc;
}

extern "C" void kernel_launch(void* const* d_in, const int* in_sizes, int n_in,
                              void* d_out, int out_size, void* d_ws, size_t ws_size,
                              hipStream_t stream) {
    const int*   x = (const int*)d_in[0];
    const float* w = (const float*)d_in[1];
    float* out = (float*)d_out;

    const size_t need = XT_ELEMS * 2 + WT_ELEMS * 2;   // ~52.6 MB
    if (ws_size >= need) {
        unsigned short* xt = (unsigned short*)d_ws;
        unsigned short* wt = (unsigned short*)((char*)d_ws + XT_ELEMS * 2);
        hipLaunchKernelGGL(xform_x, dim3(N_IMG * H_IN), dim3(256), 0, stream, x, xt);
        hipLaunchKernelGGL(xform_w, dim3(K_OUT), dim3(256), 0, stream, w, wt);
        hipLaunchKernelGGL(conv_mfma, dim3((M_PIX / 128) * 2), dim3(256), 0, stream, xt, wt, out);
    } else {
        const int total = N_IMG * K_OUT * HW_OUT;
        hipLaunchKernelGGL(conv_naive, dim3((total + 255) / 256), dim3(256), 0, stream, x, w, out);
    }
}

// Round 2
// 102.604 us; speedup vs baseline: 1.8061x; 1.8061x over previous
//
#include <hip/hip_runtime.h>
#include <stdint.h>

typedef int i32x4 __attribute__((ext_vector_type(4)));

#define N_IMG 32
#define C_IN 256
#define H_IN 56
#define W_IN 56
#define K_OUT 256
#define H_OUT 54
#define W_OUT 54
#define HW_OUT 2916          // 54*54
#define M_PIX 93312          // 32*2916
#define CHW_OUT 746496       // 256*2916

#define XT_BYTES ((size_t)N_IMG * H_IN * W_IN * C_IN)   // 25,690,112 (i8 NHWC)
#define WT_BYTES ((size_t)9 * K_OUT * C_IN)             // 589,824   (i8 [rs][k][c])

// -------- transform 1: x NCHW int32 -> NHWC i8 (clip to 0..7, exact) --------
__global__ __launch_bounds__(256) void xform_x(const int* __restrict__ x,
                                               unsigned char* __restrict__ xt) {
    const int bid = blockIdx.x;          // n*56 + h
    const int n = bid / H_IN;
    const int h = bid % H_IN;
    const int c = threadIdx.x;
    const int* src = x + ((size_t)((n * C_IN + c) * H_IN + h)) * W_IN;
    unsigned char* dst = xt + ((size_t)(n * H_IN + h) * W_IN) * C_IN + c;
    #pragma unroll
    for (int w0 = 0; w0 < W_IN; w0 += 4) {
        int4 v = *(const int4*)(src + w0);
        int a[4] = {v.x, v.y, v.z, v.w};
        #pragma unroll
        for (int j = 0; j < 4; ++j) {
            int q = a[j] < 0 ? 0 : (a[j] > 7 ? 7 : a[j]);
            dst[(size_t)(w0 + j) * C_IN] = (unsigned char)q;
        }
    }
}

// -------- transform 2: weight OIHW fp32 -> [rs][k][c] i8 (trunc to int) --------
__global__ __launch_bounds__(256) void xform_w(const float* __restrict__ w,
                                               unsigned char* __restrict__ wt) {
    const int k = blockIdx.x;
    const int c = threadIdx.x;
    const float* src = w + ((size_t)k * C_IN + c) * 9;
    #pragma unroll
    for (int rs = 0; rs < 9; ++rs) {
        int iv = (int)src[rs];   // truncation == astype(int32); values 0..6
        wt[((size_t)rs * K_OUT + k) * C_IN + c] = (unsigned char)iv;
    }
}

// -------- async global->LDS (width 16) --------
__device__ __forceinline__ void gload_lds16(const void* g, void* l) {
    __builtin_amdgcn_global_load_lds(
        (const __attribute__((address_space(1))) uint32_t*)g,
        (__attribute__((address_space(3))) uint32_t*)l,
        16, 0, 0);
}

// -------- main implicit-GEMM conv (i8): BM=128 pix, BN=128 ch, BK=128 c, 4 waves --------
__global__ __launch_bounds__(256) void conv_mfma(const unsigned char* __restrict__ xt,
                                                 const unsigned char* __restrict__ wt,
                                                 float* __restrict__ out) {
    __shared__ unsigned char As[128 * 128];   // 16 KiB: [pixel_row][c-chunk] swizzled
    __shared__ unsigned char Bs[128 * 128];   // 16 KiB: [out_ch_row][c-chunk] swizzled

    const int t   = threadIdx.x;
    const int l   = t & 63;
    const int wid = t >> 6;
    const int wr  = wid >> 1;    // wave row (0..1) -> 64 pixels
    const int wc  = wid & 1;     // wave col (0..1) -> 64 channels
    const int mb  = blockIdx.x >> 1;   // 729 M-blocks
    const int nb  = blockIdx.x & 1;    // 2 N-blocks

    // staging: per round i, lane covers row = i*32 + wid*8 + (l>>3), slot (l&7).
    // Both-sides swizzle: LDS slot s of row holds data chunk s^(row&7); here
    // row&7 == l>>3, so per-lane source chunk = (l&7)^(l>>3)  (constant).
    const int cs = (((l & 7) ^ (l >> 3)) << 4);  // byte offset within 128B row

    int abase[4], bbase[4];
    #pragma unroll
    for (int i = 0; i < 4; ++i) {
        const int row = i * 32 + wid * 8 + (l >> 3);
        const int m   = mb * 128 + row;
        const int n   = m / HW_OUT;
        const int rem = m - n * HW_OUT;
        const int ho  = rem / W_OUT;
        const int wo  = rem - ho * W_OUT;
        abase[i] = (((n * H_IN + ho) * W_IN + wo) << 8) + cs;   // 256 B per NHWC pixel
        bbase[i] = ((nb * 128 + row) << 8) + cs;                // 256 B per k-row of wt[rs]
    }

    i32x4 acc[4][4];
    #pragma unroll
    for (int i = 0; i < 4; ++i)
        #pragma unroll
        for (int j = 0; j < 4; ++j)
            acc[i][j] = (i32x4){0, 0, 0, 0};

    const char* xb = (const char*)xt;
    const char* wb = (const char*)wt;
    char* Ab = (char*)As;
    char* Bb = (char*)Bs;

    const int lrow = l & 15;
    const int lk   = (l >> 4) << 4;   // fragment k-subchunk byte offset (0/16/32/48)

    for (int ks = 0; ks < 18; ++ks) {
        const int rs  = ks >> 1;                   // tap index 0..8
        const int c0b = (ks & 1) << 7;             // c-chunk byte offset (0 or 128)
        const int r   = rs / 3;
        const int s   = rs - r * 3;
        const int astep = ((r * W_IN + s) << 8) + c0b;
        const int bstep = rs * (K_OUT * C_IN) + c0b;

        __syncthreads();   // previous tile's reads complete before overwrite
        #pragma unroll
        for (int i = 0; i < 4; ++i) {
            gload_lds16(xb + abase[i] + astep, Ab + i * 4096 + wid * 1024);
            gload_lds16(wb + bbase[i] + bstep, Bb + i * 4096 + wid * 1024);
        }
        __syncthreads();   // compiler drains vmcnt(0) before barrier -> tiles ready

        i32x4 af[4][2], bfv[4][2];
        #pragma unroll
        for (int f = 0; f < 4; ++f) {
            const int arow = wr * 64 + f * 16 + lrow;
            const int brow = wc * 64 + f * 16 + lrow;
            const int asw = (arow & 7) << 4;
            const int bsw = (brow & 7) << 4;
            #pragma unroll
            for (int kk = 0; kk < 2; ++kk) {
                const int chb = (kk << 6) + lk;
                af[f][kk]  = *(const i32x4*)(Ab + (arow << 7) + (chb ^ asw));
                bfv[f][kk] = *(const i32x4*)(Bb + (brow << 7) + (chb ^ bsw));
            }
        }
        #pragma unroll
        for (int mf = 0; mf < 4; ++mf)
            #pragma unroll
            for (int nf = 0; nf < 4; ++nf)
                #pragma unroll
                for (int kk = 0; kk < 2; ++kk)
                    acc[mf][nf] = __builtin_amdgcn_mfma_i32_16x16x64_i8(
                        af[mf][kk], bfv[nf][kk], acc[mf][nf], 0, 0, 0);
    }

    // epilogue: C/D layout col=lane&15, row=(lane>>4)*4+reg (dtype-independent)
    const int c16    = l & 15;
    const int p4     = (l >> 4) << 2;
    const int chbase = nb * 128 + wc * 64 + c16;
    #pragma unroll
    for (int mf = 0; mf < 4; ++mf) {
        #pragma unroll
        for (int j = 0; j < 4; ++j) {
            const int m   = mb * 128 + wr * 64 + mf * 16 + p4 + j;
            const int n   = m / HW_OUT;
            const int rem = m - n * HW_OUT;
            float* obase = out + (size_t)n * CHW_OUT + rem;
            #pragma unroll
            for (int nf = 0; nf < 4; ++nf)
                obase[(size_t)(chbase + nf * 16) * HW_OUT] = (float)acc[mf][nf][j];
        }
    }
}

// -------- fallback (only if ws too small): naive direct conv, exact --------
__global__ __launch_bounds__(256) void conv_naive(const int* __restrict__ x,
                                                  const float* __restrict__ w,
                                                  float* __restrict__ out) {
    int idx = blockIdx.x * 256 + threadIdx.x;
    if (idx >= N_IMG * K_OUT * HW_OUT) return;
    const int wo = idx % W_OUT;
    int tmp = idx / W_OUT;
    const int ho = tmp % H_OUT; tmp /= H_OUT;
    const int k = tmp % K_OUT;
    const int n = tmp / K_OUT;
    float acc = 0.f;
    for (int c = 0; c < C_IN; ++c) {
        const int* xp = x + ((size_t)((n * C_IN + c) * H_IN + ho)) * W_IN + wo;
        const float* wp = w + ((size_t)(k * C_IN + c)) * 9;
        #pragma unroll
        for (int r = 0; r < 3; ++r)
            #pragma unroll
            for (int s = 0; s < 3; ++s) {
                int xv = xp[r * W_IN + s];
                xv = xv < 0 ? 0 : (xv > 7 ? 7 : xv);
                acc += (float)xv * (float)(int)wp[r * 3 + s];
            }
    }
    out[idx] = acc;
}

extern "C" void kernel_launch(void* const* d_in, const int* in_sizes, int n_in,
                              void* d_out, int out_size, void* d_ws, size_t ws_size,
                              hipStream_t stream) {
    const int*   x = (const int*)d_in[0];
    const float* w = (const float*)d_in[1];
    float* out = (float*)d_out;

    const size_t need = XT_BYTES + WT_BYTES;   // ~26.3 MB
    if (ws_size >= need) {
        unsigned char* xt = (unsigned char*)d_ws;
        unsigned char* wt = (unsigned char*)((char*)d_ws + XT_BYTES);
        hipLaunchKernelGGL(xform_x, dim3(N_IMG * H_IN), dim3(256), 0, stream, x, xt);
        hipLaunchKernelGGL(xform_w, dim3(K_OUT), dim3(256), 0, stream, w, wt);
        hipLaunchKernelGGL(conv_mfma, dim3((M_PIX / 128) * 2), dim3(256), 0, stream, xt, wt, out);
    } else {
        const int total = N_IMG * K_OUT * HW_OUT;
        hipLaunchKernelGGL(conv_naive, dim3((total + 255) / 256), dim3(256), 0, stream, x, w, out);
    }
}